// Round 3
// baseline (744.756 us; speedup 1.0000x reference)
//
#include <hip/hip_runtime.h>
#include <hip/hip_bf16.h>

// B=2048 rows, T=2048 steps, H=32. Thread = (b, k, half): wave = ONE batch row
// (lane = k + 32*half). Each thread holds the k-slice [16*half,16*half+16) of
// the 4 gate rows {k,32+k,64+k,96+k} -> 64 weight floats, asm-laundered so the
// compiler cannot rematerialize them from global. 2048 waves = 2 waves/SIMD.
// Per step: 32 v_pk_fma_f32 partial dots, cross-half reduce via shfl_xor(32),
// split activations (half0: sigmoid i,f; half1: tanh g, sigmoid o) with a
// unified A*rcp(1+exp2(B*x))+C form, value swap, c/h update redundantly in
// both halves, paired 2-step output stores. No barriers anywhere.

#define Bsz 2048
#define Tsz 2048
#define Hsz 32

typedef float v2f __attribute__((ext_vector_type(2)));

__device__ __forceinline__ float fast_rcp(float x) {
    return __builtin_amdgcn_rcpf(x);
}
__device__ __forceinline__ float fast_exp2(float x) {
    return __builtin_amdgcn_exp2f(x);
}
__device__ __forceinline__ float fast_tanh(float x) {
    float e = fast_exp2(-2.885390082f * x);
    return __fmaf_rn(2.0f, fast_rcp(1.0f + e), -1.0f);
}

#if __has_builtin(__builtin_elementwise_fma)
__device__ __forceinline__ v2f pkfma(v2f a, v2f b, v2f c) {
    return __builtin_elementwise_fma(a, b, c);
}
#else
__device__ __forceinline__ v2f pkfma(v2f a, v2f b, v2f c) {
    v2f r; r.x = __fmaf_rn(a.x, b.x, c.x); r.y = __fmaf_rn(a.y, b.y, c.y); return r;
}
#endif

__global__ __launch_bounds__(256, 2) void lstm_fwd_kernel(
    const float* __restrict__ x,      // (B, T)
    const float* __restrict__ w_ih,   // (4H, 1)
    const float* __restrict__ w_hh,   // (4H, H)
    const float* __restrict__ b_ih,   // (4H,)
    const float* __restrict__ b_hh,   // (4H,)
    float* __restrict__ out)          // (B, T*H)
{
    __shared__ float hbuf[4][32];     // one 128B h-line per wave(row)

    const int lane = threadIdx.x & 63;
    const int k    = lane & 31;
    const int hf   = lane >> 5;                                   // half: 0/1
    const int wv   = __builtin_amdgcn_readfirstlane((int)(threadIdx.x >> 6));
    const int b    = blockIdx.x * 4 + wv;

    // ---- register-resident weights: 4 gates x 16 k-slice = 32 v2f ----
    v2f   W[4][8];
    float wi[4], bs[4];
#pragma unroll
    for (int g = 0; g < 4; ++g) {
        const int j = g * 32 + k;
        wi[g] = w_ih[j];
        bs[g] = b_ih[j] + b_hh[j];
        const float4* wr =
            reinterpret_cast<const float4*>(w_hh + (size_t)j * 32 + hf * 16);
#pragma unroll
        for (int q = 0; q < 4; ++q) {
            float4 v = wr[q];
            W[g][2 * q]     = (v2f){v.x, v.y};
            W[g][2 * q + 1] = (v2f){v.z, v.w};
        }
    }
    // launder: block rematerialization of the weight loads inside the T loop
#pragma unroll
    for (int g = 0; g < 4; ++g) {
#pragma unroll
        for (int q = 0; q < 8; ++q) asm volatile("" : "+v"(W[g][q]));
        asm volatile("" : "+v"(wi[g]), "+v"(bs[g]));
    }

    // unified activation constants: r = A*rcp(1+exp2(B*v)) + C
    // half0 value1 = sigmoid(p_i); half1 value1 = tanh(p_g); value2 always sigmoid
    const float A1 = hf ? 2.0f : 1.0f;
    const float B1 = hf ? -2.885390082f : -1.442695041f;
    const float C1 = hf ? -1.0f : 0.0f;
    const float BS = -1.442695041f;

    float c = 0.0f, h = 0.0f, hprev = 0.0f;
    hbuf[wv][k] = 0.0f;               // same-addr dual write: benign

    const float* xrow  = x + (size_t)b * Tsz;
    float*       obase = out + (size_t)b * (size_t)(Tsz * Hsz);
    const int    sidx  = hf * 32 + k; // paired-store lane offset (2 rows/store)

    float xs[8], xn[8];
#pragma unroll
    for (int j = 0; j < 8; ++j) xs[j] = xrow[j];

    for (int t0 = 0; t0 < Tsz; t0 += 8) {
        const int tn = (t0 + 8 < Tsz) ? (t0 + 8) : t0;   // safe prefetch base
#pragma unroll
        for (int j = 0; j < 8; ++j) xn[j] = xrow[tn + j];

#pragma unroll
        for (int tt = 0; tt < 8; ++tt) {
            // previous h, this thread's 16-float slice (4 x ds_read_b128)
            const float4* hr =
                reinterpret_cast<const float4*>(&hbuf[wv][hf * 16]);
            float4 h0 = hr[0], h1 = hr[1], h2 = hr[2], h3 = hr[3];
            v2f hv0 = (v2f){h0.x, h0.y}, hv1 = (v2f){h0.z, h0.w};
            v2f hv2 = (v2f){h1.x, h1.y}, hv3 = (v2f){h1.z, h1.w};
            v2f hv4 = (v2f){h2.x, h2.y}, hv5 = (v2f){h2.z, h2.w};
            v2f hv6 = (v2f){h3.x, h3.y}, hv7 = (v2f){h3.z, h3.w};
            const float xt = xs[tt];

            float p[4];
#pragma unroll
            for (int g = 0; g < 4; ++g) {
                v2f a = pkfma(W[g][0], hv0, (v2f){0.0f, 0.0f});
                a = pkfma(W[g][1], hv1, a);
                a = pkfma(W[g][2], hv2, a);
                a = pkfma(W[g][3], hv3, a);
                a = pkfma(W[g][4], hv4, a);
                a = pkfma(W[g][5], hv5, a);
                a = pkfma(W[g][6], hv6, a);
                a = pkfma(W[g][7], hv7, a);
                float s = a.x + a.y;
                s += __shfl_xor(s, 32);                  // cross-half reduce
                p[g] = s + __fmaf_rn(wi[g], xt, bs[g]);  // bias AFTER reduce
            }

            // split activations: half0 -> sigmoid(p0), sigmoid(p1)
            //                    half1 -> tanh(p2),   sigmoid(p3)
            const float v1 = hf ? p[2] : p[0];
            const float v2 = hf ? p[3] : p[1];
            const float r1 = __fmaf_rn(A1, fast_rcp(1.0f + fast_exp2(B1 * v1)), C1);
            const float r2 = fast_rcp(1.0f + fast_exp2(BS * v2));
            const float a2 = __shfl_xor(r1, 32);
            const float b2 = __shfl_xor(r2, 32);
            const float i_ = hf ? a2 : r1;
            const float g_ = hf ? r1 : a2;
            const float f_ = hf ? b2 : r2;
            const float o_ = hf ? r2 : b2;

            c = __fmaf_rn(f_, c, i_ * g_);
            h = o_ * fast_tanh(c);

            hbuf[wv][k] = h;          // both halves, same value: benign

            if (tt & 1) {             // paired store: rows t-1 (hf=0), t (hf=1)
                const float v = hf ? h : hprev;
                obase[(size_t)(t0 + tt - 1) * Hsz + sidx] = v;
            } else {
                hprev = h;
            }
        }
#pragma unroll
        for (int j = 0; j < 8; ++j) xs[j] = xn[j];
    }
}

extern "C" void kernel_launch(void* const* d_in, const int* in_sizes, int n_in,
                              void* d_out, int out_size, void* d_ws, size_t ws_size,
                              hipStream_t stream) {
    const float* x    = (const float*)d_in[0];
    const float* w_ih = (const float*)d_in[1];
    const float* w_hh = (const float*)d_in[2];
    const float* b_ih = (const float*)d_in[3];
    const float* b_hh = (const float*)d_in[4];
    float* out = (float*)d_out;

    dim3 grid(Bsz / 4);   // 512 blocks = 2 per CU -> 2 waves/SIMD
    dim3 block(256);      // 4 waves, each = one batch row (32 k x 2 halves)
    lstm_fwd_kernel<<<grid, block, 0, stream>>>(x, w_ih, w_hh, b_ih, b_hh, out);
}